// Round 2
// baseline (91776.971 us; speedup 1.0000x reference)
//
#include <hip/hip_runtime.h>
#include <hip/hip_bf16.h>

// Round 2: fp32 in/out (reference dtypes are float32 — round-1 NaN was from
// misreading fp32 buffers as bf16).
// Algebra exploited:
//  - seq_len==1 softmax == 1  =>  attn(x) = (x@Wv+bv)@Wo+bo  (Wq/Wk/bq/bk dead)
//  - activations kept TRANSPOSED [feature][batch=64] in ws so A-loads are
//    coalesced (lane = batch index); weight loads are wave-uniform broadcasts.

#define T_STEPS 128
#define LAT 256

// z [64,256] row-major -> zT [256][64]
__global__ void k_transpose_in(const float* __restrict__ z, float* __restrict__ zT) {
  int i = blockIdx.x * 256 + threadIdx.x;   // 16384 elems
  int m = i >> 8, l = i & 255;
  zT[l * 64 + m] = z[i];
}

__global__ void k_copy2(const float* __restrict__ s, float* __restrict__ d1,
                        float* __restrict__ d2) {
  int i = blockIdx.x * 256 + threadIdx.x;   // 65536 elems
  float v = s[i]; d1[i] = v; d2[i] = v;
}

// C_T[n][m] = act(sum_k A_T[k][m]*W[k][n] + bias[n]) ; W row-major [K,N] fp32.
// block 256 = 4 waves; each wave handles one output column; lane = batch row.
// grid.x = N/4. Optional bf16?no — fp32 out slice for the head matmul.
template <int ACT>
__global__ void k_gemm(const float* __restrict__ A_T, const float* __restrict__ W,
                       const float* __restrict__ bias, float* __restrict__ C_T,
                       int K, int N, float* __restrict__ outp, int tstep) {
  const int m = threadIdx.x & 63;
  const int wv = threadIdx.x >> 6;
  const int c = blockIdx.x * 4 + wv;
  float acc0 = 0.f, acc1 = 0.f;
  const float* ap = A_T + m;
  const float* wp = W + c;
  int k = 0;
  #pragma unroll 4
  for (; k + 1 < K; k += 2) {
    acc0 = fmaf(ap[k * 64],        wp[k * N],        acc0);
    acc1 = fmaf(ap[(k + 1) * 64],  wp[(k + 1) * N],  acc1);
  }
  float v0 = acc0 + acc1 + bias[c];
  if (ACT) v0 = fmaxf(v0, 0.f);
  C_T[c * 64 + m] = v0;
  if (outp != nullptr) {
    outp[(m * T_STEPS + tstep) * LAT + c] = v0;
  }
}

// Fused GRU cell: gates + combine for one hidden column per wave.
// Gate order along 3*HID: (r, z, n). h' = (1-z)*n + z*h,
// n = tanh(gi_n + r*gh_n), r/z = sigmoid(gi+gh).
// grid 256, block 256 (4 waves -> 4 columns/block).
__global__ void k_gru(const float* __restrict__ xT, const float* __restrict__ hT,
                      const float* __restrict__ Wih, const float* __restrict__ Whh,
                      const float* __restrict__ bih, const float* __restrict__ bhh,
                      float* __restrict__ hnT) {
  const int m = threadIdx.x & 63;
  const int wv = threadIdx.x >> 6;
  const int c = blockIdx.x * 4 + wv;
  float racc = 0, zacc = 0, iacc = 0, nacc = 0;
  const float* xp = xT + m;
  const float* hp = hT + m;
  const float* wi = Wih + c;
  const float* wh = Whh + c;
  #pragma unroll 2
  for (int k = 0; k < 1024; ++k) {
    float a = xp[k * 64];
    float h = hp[k * 64];
    const float* wik = wi + k * 3072;
    const float* whk = wh + k * 3072;
    racc = fmaf(a, wik[0],    racc); racc = fmaf(h, whk[0],    racc);
    zacc = fmaf(a, wik[1024], zacc); zacc = fmaf(h, whk[1024], zacc);
    iacc = fmaf(a, wik[2048], iacc);
    nacc = fmaf(h, whk[2048], nacc);
  }
  float r  = 1.f / (1.f + expf(-(racc + bih[c] + bhh[c])));
  float zg = 1.f / (1.f + expf(-(zacc + bih[1024 + c] + bhh[1024 + c])));
  float nn = tanhf(iacc + bih[2048 + c] + r * (nacc + bhh[2048 + c]));
  float hprev = hT[c * 64 + m];
  hnT[c * 64 + m] = (1.f - zg) * nn + zg * hprev;
}

extern "C" void kernel_launch(void* const* d_in, const int* in_sizes, int n_in,
                              void* d_out, int out_size, void* d_ws, size_t ws_size,
                              hipStream_t stream) {
  const float* z_start = (const float*)d_in[0];
  // d_in[1] = max_len (int scalar) — fixed at 128 by the problem.
  const float* w1   = (const float*)d_in[2];
  const float* b1   = (const float*)d_in[3];
  const float* w2   = (const float*)d_in[4];
  const float* b2   = (const float*)d_in[5];
  // d_in[6..9] = Wq, bq, Wk, bk — provably unused (softmax over 1 key == 1).
  const float* Wv   = (const float*)d_in[10];
  const float* bv   = (const float*)d_in[11];
  const float* Wo   = (const float*)d_in[12];
  const float* bo   = (const float*)d_in[13];
  const float* Wih0 = (const float*)d_in[14];
  const float* Whh0 = (const float*)d_in[15];
  const float* bih0 = (const float*)d_in[16];
  const float* bhh0 = (const float*)d_in[17];
  const float* Wih1 = (const float*)d_in[18];
  const float* Whh1 = (const float*)d_in[19];
  const float* bih1 = (const float*)d_in[20];
  const float* bhh1 = (const float*)d_in[21];
  const float* Wh   = (const float*)d_in[22];
  const float* bh   = (const float*)d_in[23];
  float* out = (float*)d_out;

  float* ws  = (float*)d_ws;
  float* zsT = ws;                    // 256*64
  float* vT  = zsT + 16384;           // 1024*64
  float* xaT = vT + 65536;
  float* t1T = xaT + 65536;
  float* ginT = t1T + 65536;
  float* nzT = ginT + 65536;          // 256*64
  float* h1T = nzT + 16384;           // 2 * 1024*64 (ping-pong)
  float* h2T = h1T + 2 * 65536;       // 2 * 1024*64

  // h0p = relu(z@w1+b1)@w2 + b2  (no outer relu); h1 = h2 = gin = h0p
  k_transpose_in<<<64, 256, 0, stream>>>(z_start, zsT);
  k_gemm<1><<<256, 256, 0, stream>>>(zsT, w1, b1, t1T, 256, 1024, nullptr, 0);
  k_gemm<0><<<256, 256, 0, stream>>>(t1T, w2, b2, h1T, 1024, 1024, nullptr, 0);
  k_copy2<<<256, 256, 0, stream>>>(h1T, h2T, ginT);

  for (int t = 0; t < T_STEPS; ++t) {
    float* h1p = h1T + (t & 1) * 65536;
    float* h1n = h1T + ((t + 1) & 1) * 65536;
    float* h2p = h2T + (t & 1) * 65536;
    float* h2n = h2T + ((t + 1) & 1) * 65536;
    // attn: xa = (gin@Wv+bv)@Wo+bo
    k_gemm<0><<<256, 256, 0, stream>>>(ginT, Wv, bv, vT, 1024, 1024, nullptr, 0);
    k_gemm<0><<<256, 256, 0, stream>>>(vT, Wo, bo, xaT, 1024, 1024, nullptr, 0);
    // GRU stack
    k_gru<<<256, 256, 0, stream>>>(xaT, h1p, Wih0, Whh0, bih0, bhh0, h1n);
    k_gru<<<256, 256, 0, stream>>>(h1n, h2p, Wih1, Whh1, bih1, bhh1, h2n);
    // head: nz = h2n@Wh+bh (also writes fp32 output slice for step t)
    k_gemm<0><<<64, 256, 0, stream>>>(h2n, Wh, bh, nzT, 1024, 256, out, t);
    // gin' = relu( relu(nz@w1+b1)@w2 + b2 )
    k_gemm<1><<<256, 256, 0, stream>>>(nzT, w1, b1, t1T, 256, 1024, nullptr, 0);
    k_gemm<1><<<256, 256, 0, stream>>>(t1T, w2, b2, ginT, 1024, 1024, nullptr, 0);
  }
}

// Round 3
// 45498.328 us; speedup vs baseline: 2.0172x; 2.0172x over previous
//
#include <hip/hip_runtime.h>
#include <hip/hip_cooperative_groups.h>

namespace cg = cooperative_groups;

#define TSTEP 128
#define HIDD 1024
#define LATD 256

// ---------------------------------------------------------------------------
// Persistent cooperative kernel. Grid 256 x 512. All activations fp32,
// transposed [feature][batch=64] (lane = batch). Folds:
//   Wvo   = Wv@Wo                      (attn for seq_len==1: softmax==1)
//   Wvoih = Wvo@Wih0, bfold = (bv@Wo+bo)@Wih0 + bih0   -> attn phase gone
//   WhW1  = Wh@w1,    bhw1  = bh@w1+b1                 -> nz off critical path
// Per step: GRU0 -> GRU1 -> {t1 + nz->out} -> gin  (4 grid syncs)
// ---------------------------------------------------------------------------

struct P {
  const float *z, *w1, *b1, *w2, *b2, *Wv, *bv, *Wo, *bo;
  const float *Wih0, *Whh0, *bih0, *bhh0, *Wih1, *Whh1, *bih1, *bhh1, *Wh, *bh;
  float *out;
  float *Wvo, *Wvoih, *WhW1, *bvo, *bfold, *bhw1;
  float *zT, *t1a, *gin, *t1, *h1a, *h1b, *h2a, *h2b;
};

// C[K x N] = A[K x J] @ B[J x N]; 4 rows/block (grid 256 covers K=1024 rows),
// 128 threads/row, thread covers cols c = (tid&127) + i*128 (coalesced).
template <int J, int N, int CPT>
__device__ inline void matmat(const float* __restrict__ A, const float* __restrict__ B,
                              float* __restrict__ C) {
  const int tid = threadIdx.x;
  const int r = blockIdx.x * 4 + (tid >> 7);
  const int c0 = tid & 127;
  float acc[CPT];
#pragma unroll
  for (int i = 0; i < CPT; ++i) acc[i] = 0.f;
  const float* ar = A + r * J;
#pragma unroll 2
  for (int j = 0; j < J; ++j) {
    float av = ar[j];
    const float* br = B + j * N + c0;
#pragma unroll
    for (int i = 0; i < CPT; ++i) acc[i] = fmaf(av, br[i * 128], acc[i]);
  }
  float* cr = C + r * N + c0;
#pragma unroll
  for (int i = 0; i < CPT; ++i) cr[i * 128] = acc[i];
}

// outv[c] = v @ M[:,c] + badd[c], for blocks [blk0, blk0+nblk)
__device__ inline void vecmat(const float* __restrict__ v, const float* __restrict__ M,
                              const float* __restrict__ badd, float* __restrict__ outv,
                              int J, int N, int blk0, int nblk) {
  int b = blockIdx.x;
  if (b < blk0 || b >= blk0 + nblk) return;
  int gid = (b - blk0) * 512 + threadIdx.x;
  if (gid >= N) return;
  float acc = 0.f;
#pragma unroll 4
  for (int j = 0; j < J; ++j) acc = fmaf(v[j], M[j * N + gid], acc);
  outv[gid] = acc + badd[gid];
}

// C_T[c][m] = act(A_T @ W[:,c] + bias[c]); N=1024 cols, 4/block, 2-way K-split.
__device__ inline void gemv1024(const float* __restrict__ A, const float* __restrict__ W,
                                const float* __restrict__ bias, int K, int relu,
                                float* __restrict__ C, float* __restrict__ C2,
                                float* __restrict__ C3, float* red) {
  const int tid = threadIdx.x;
  const int m = tid & 63, w = tid >> 6;
  const int j = w & 3, hh = w >> 2;
  const int c = blockIdx.x * 4 + j;
  const int kh = K >> 1;
  const float* a = A + m + (hh * kh) * 64;
  const float* wp = W + c + (hh * kh) * 1024;
  float acc = 0.f;
#pragma unroll 8
  for (int k = 0; k < kh; ++k) acc = fmaf(a[k * 64], wp[k * 1024], acc);
  if (hh) red[j * 64 + m] = acc;
  __syncthreads();
  if (!hh) {
    float v = acc + red[j * 64 + m] + bias[c];
    if (relu) v = fmaxf(v, 0.f);
    C[c * 64 + m] = v;
    if (C2) C2[c * 64 + m] = v;
    if (C3) C3[c * 64 + m] = v;
  }
  __syncthreads();
}

// Fused GRU cell phase: 4 cols/block, 2-way K-split, gates r/z/n.
__device__ inline void gru(const float* __restrict__ xT, const float* __restrict__ hT,
                           const float* __restrict__ Wx, const float* __restrict__ Wm,
                           const float* __restrict__ bx, const float* __restrict__ bm,
                           float* __restrict__ hn, float* red) {
  const int tid = threadIdx.x;
  const int m = tid & 63, w = tid >> 6;
  const int j = w & 3, hh = w >> 2;
  const int c = blockIdx.x * 4 + j;
  const float* xp = xT + m + hh * 512 * 64;
  const float* hp = hT + m + hh * 512 * 64;
  const float* wx = Wx + c + hh * 512 * 3072;
  const float* wh = Wm + c + hh * 512 * 3072;
  float ra = 0.f, za = 0.f, ia = 0.f, na = 0.f;
#pragma unroll 4
  for (int k = 0; k < 512; ++k) {
    float a = xp[k * 64], h = hp[k * 64];
    const float* wxk = wx + k * 3072;
    const float* whk = wh + k * 3072;
    ra = fmaf(a, wxk[0], ra);    ra = fmaf(h, whk[0], ra);
    za = fmaf(a, wxk[1024], za); za = fmaf(h, whk[1024], za);
    ia = fmaf(a, wxk[2048], ia);
    na = fmaf(h, whk[2048], na);
  }
  float* rj = red + j * 256;
  if (hh) { rj[m] = ra; rj[64 + m] = za; rj[128 + m] = ia; rj[192 + m] = na; }
  __syncthreads();
  if (!hh) {
    ra += rj[m]; za += rj[64 + m]; ia += rj[128 + m]; na += rj[192 + m];
    float r  = 1.f / (1.f + expf(-(ra + bx[c] + bm[c])));
    float zg = 1.f / (1.f + expf(-(za + bx[1024 + c] + bm[1024 + c])));
    float nn = tanhf(ia + bx[2048 + c] + r * (na + bm[2048 + c]));
    hn[c * 64 + m] = (1.f - zg) * nn + zg * hT[c * 64 + m];
  }
  __syncthreads();
}

// Phase 3: t1 = relu(h2n@WhW1 + bhw1)  AND  nz = h2n@Wh + bh -> out (col/block)
__device__ inline void phase3(const P& p, int t, const float* __restrict__ h2n,
                              float* red, float* red2) {
  const int tid = threadIdx.x;
  const int m = tid & 63, w = tid >> 6;
  const int j = w & 3, hh = w >> 2;
  const int c = blockIdx.x * 4 + j;
  const float* a = h2n + m + hh * 512 * 64;
  const float* wp = p.WhW1 + c + hh * 512 * 1024;
  float acc = 0.f;
#pragma unroll 8
  for (int k = 0; k < 512; ++k) acc = fmaf(a[k * 64], wp[k * 1024], acc);
  // nz mini-GEMV: col = blockIdx.x, 8-way K-split
  const int cn = blockIdx.x;
  const float* a2 = h2n + m + w * 128 * 64;
  const float* wp2 = p.Wh + cn + w * 128 * 256;
  float an = 0.f;
#pragma unroll 8
  for (int k = 0; k < 128; ++k) an = fmaf(a2[k * 64], wp2[k * 256], an);
  if (hh) red[j * 64 + m] = acc;
  red2[w * 64 + m] = an;
  __syncthreads();
  if (!hh) {
    float v = acc + red[j * 64 + m] + p.bhw1[c];
    p.t1[c * 64 + m] = fmaxf(v, 0.f);
  }
  if (w == 0) {
    float s = an;
#pragma unroll
    for (int i = 1; i < 8; ++i) s += red2[i * 64 + m];
    p.out[(m * TSTEP + t) * LATD + cn] = s + p.bh[cn];
  }
  __syncthreads();
}

__global__ __launch_bounds__(512) void persist(P p) {
  cg::grid_group grid = cg::this_grid();
  __shared__ float red[4 * 4 * 64];
  __shared__ float red2[8 * 64];

  // ---- pre-loop precompute ----
  if (threadIdx.x < 64) {  // zT transpose (64 elems/block)
    int i = blockIdx.x * 64 + threadIdx.x;
    int m = i >> 8, l = i & 255;
    p.zT[l * 64 + m] = p.z[i];
  }
  matmat<1024, 1024, 8>(p.Wv, p.Wo, p.Wvo);
  vecmat(p.bh, p.w1, p.b1, p.bhw1, 256, 1024, 0, 2);
  vecmat(p.bv, p.Wo, p.bo, p.bvo, 1024, 1024, 2, 2);
  grid.sync();
  matmat<1024, 3072, 24>(p.Wvo, p.Wih0, p.Wvoih);
  vecmat(p.bvo, p.Wih0, p.bih0, p.bfold, 1024, 3072, 0, 6);
  grid.sync();
  matmat<256, 1024, 8>(p.Wh, p.w1, p.WhW1);
  grid.sync();
  gemv1024(p.zT, p.w1, p.b1, 256, 1, p.t1a, nullptr, nullptr, red);
  grid.sync();
  gemv1024(p.t1a, p.w2, p.b2, 1024, 0, p.h1a, p.h2a, p.gin, red);
  grid.sync();

  // ---- time loop: 4 phases/step ----
  for (int t = 0; t < TSTEP; ++t) {
    float* h1p = (t & 1) ? p.h1b : p.h1a;
    float* h1n = (t & 1) ? p.h1a : p.h1b;
    float* h2p = (t & 1) ? p.h2b : p.h2a;
    float* h2n = (t & 1) ? p.h2a : p.h2b;
    gru(p.gin, h1p, p.Wvoih, p.Whh0, p.bfold, p.bhh0, h1n, red);
    grid.sync();
    gru(h1n, h2p, p.Wih1, p.Whh1, p.bih1, p.bhh1, h2n, red);
    grid.sync();
    phase3(p, t, h2n, red, red2);
    grid.sync();
    gemv1024(p.t1, p.w2, p.b2, 1024, 1, p.gin, nullptr, nullptr, red);
    grid.sync();
  }
}

// ---------------------------------------------------------------------------
// Fallback path (round-2 verified multi-kernel), used if ws too small or
// cooperative launch unavailable.
// ---------------------------------------------------------------------------
__global__ void fb_transpose(const float* __restrict__ z, float* __restrict__ zT) {
  int i = blockIdx.x * 256 + threadIdx.x;
  int m = i >> 8, l = i & 255;
  zT[l * 64 + m] = z[i];
}
__global__ void fb_copy2(const float* __restrict__ s, float* __restrict__ d1,
                         float* __restrict__ d2) {
  int i = blockIdx.x * 256 + threadIdx.x;
  float v = s[i]; d1[i] = v; d2[i] = v;
}
template <int ACT>
__global__ void fb_gemm(const float* __restrict__ A_T, const float* __restrict__ W,
                        const float* __restrict__ bias, float* __restrict__ C_T,
                        int K, int N, float* __restrict__ outp, int tstep) {
  const int m = threadIdx.x & 63;
  const int wv = threadIdx.x >> 6;
  const int c = blockIdx.x * 4 + wv;
  float acc0 = 0.f, acc1 = 0.f;
  const float* ap = A_T + m;
  const float* wp = W + c;
#pragma unroll 4
  for (int k = 0; k + 1 < K; k += 2) {
    acc0 = fmaf(ap[k * 64], wp[k * N], acc0);
    acc1 = fmaf(ap[(k + 1) * 64], wp[(k + 1) * N], acc1);
  }
  float v0 = acc0 + acc1 + bias[c];
  if (ACT) v0 = fmaxf(v0, 0.f);
  C_T[c * 64 + m] = v0;
  if (outp != nullptr) outp[(m * TSTEP + tstep) * LATD + c] = v0;
}
__global__ void fb_gru(const float* __restrict__ xT, const float* __restrict__ hT,
                       const float* __restrict__ Wih, const float* __restrict__ Whh,
                       const float* __restrict__ bih, const float* __restrict__ bhh,
                       float* __restrict__ hnT) {
  const int m = threadIdx.x & 63;
  const int wv = threadIdx.x >> 6;
  const int c = blockIdx.x * 4 + wv;
  float racc = 0, zacc = 0, iacc = 0, nacc = 0;
  const float* xp = xT + m;
  const float* hp = hT + m;
  const float* wi = Wih + c;
  const float* wh = Whh + c;
#pragma unroll 2
  for (int k = 0; k < 1024; ++k) {
    float a = xp[k * 64];
    float h = hp[k * 64];
    const float* wik = wi + k * 3072;
    const float* whk = wh + k * 3072;
    racc = fmaf(a, wik[0], racc); racc = fmaf(h, whk[0], racc);
    zacc = fmaf(a, wik[1024], zacc); zacc = fmaf(h, whk[1024], zacc);
    iacc = fmaf(a, wik[2048], iacc);
    nacc = fmaf(h, whk[2048], nacc);
  }
  float r = 1.f / (1.f + expf(-(racc + bih[c] + bhh[c])));
  float zg = 1.f / (1.f + expf(-(zacc + bih[1024 + c] + bhh[1024 + c])));
  float nn = tanhf(iacc + bih[2048 + c] + r * (nacc + bhh[2048 + c]));
  hnT[c * 64 + m] = (1.f - zg) * nn + zg * hT[c * 64 + m];
}

extern "C" void kernel_launch(void* const* d_in, const int* in_sizes, int n_in,
                              void* d_out, int out_size, void* d_ws, size_t ws_size,
                              hipStream_t stream) {
  const float* z_start = (const float*)d_in[0];
  const float* w1 = (const float*)d_in[2];
  const float* b1 = (const float*)d_in[3];
  const float* w2 = (const float*)d_in[4];
  const float* b2 = (const float*)d_in[5];
  const float* Wv = (const float*)d_in[10];
  const float* bv = (const float*)d_in[11];
  const float* Wo = (const float*)d_in[12];
  const float* bo = (const float*)d_in[13];
  const float* Wih0 = (const float*)d_in[14];
  const float* Whh0 = (const float*)d_in[15];
  const float* bih0 = (const float*)d_in[16];
  const float* bhh0 = (const float*)d_in[17];
  const float* Wih1 = (const float*)d_in[18];
  const float* Whh1 = (const float*)d_in[19];
  const float* bih1 = (const float*)d_in[20];
  const float* bhh1 = (const float*)d_in[21];
  const float* Wh = (const float*)d_in[22];
  const float* bh = (const float*)d_in[23];
  float* out = (float*)d_out;
  float* ws = (float*)d_ws;

  const size_t need = (size_t)(1048576 + 3145728 + 1048576 + 1024 + 3072 + 1024 +
                               16384 + 65536 * 3 + 65536 * 4) * 4;
  if (ws_size >= need) {
    P p;
    p.z = z_start; p.w1 = w1; p.b1 = b1; p.w2 = w2; p.b2 = b2;
    p.Wv = Wv; p.bv = bv; p.Wo = Wo; p.bo = bo;
    p.Wih0 = Wih0; p.Whh0 = Whh0; p.bih0 = bih0; p.bhh0 = bhh0;
    p.Wih1 = Wih1; p.Whh1 = Whh1; p.bih1 = bih1; p.bhh1 = bhh1;
    p.Wh = Wh; p.bh = bh; p.out = out;
    float* q = ws;
    p.Wvo = q; q += 1048576;
    p.Wvoih = q; q += 3145728;
    p.WhW1 = q; q += 1048576;
    p.bvo = q; q += 1024;
    p.bfold = q; q += 3072;
    p.bhw1 = q; q += 1024;
    p.zT = q; q += 16384;
    p.t1a = q; q += 65536;
    p.gin = q; q += 65536;
    p.t1 = q; q += 65536;
    p.h1a = q; q += 65536;
    p.h1b = q; q += 65536;
    p.h2a = q; q += 65536;
    p.h2b = q; q += 65536;
    void* args[] = { &p };
    hipError_t e = hipLaunchCooperativeKernel((const void*)persist, dim3(256),
                                              dim3(512), args, 0, stream);
    if (e == hipSuccess) return;
  }

  // -------- fallback: verified round-2 path --------
  float* zsT = ws;
  float* vT = zsT + 16384;
  float* xaT = vT + 65536;
  float* t1T = xaT + 65536;
  float* ginT = t1T + 65536;
  float* nzT = ginT + 65536;
  float* h1T = nzT + 16384;
  float* h2T = h1T + 2 * 65536;

  fb_transpose<<<64, 256, 0, stream>>>(z_start, zsT);
  fb_gemm<1><<<256, 256, 0, stream>>>(zsT, w1, b1, t1T, 256, 1024, nullptr, 0);
  fb_gemm<0><<<256, 256, 0, stream>>>(t1T, w2, b2, h1T, 1024, 1024, nullptr, 0);
  fb_copy2<<<256, 256, 0, stream>>>(h1T, h2T, ginT);
  for (int t = 0; t < TSTEP; ++t) {
    float* h1p = h1T + (t & 1) * 65536;
    float* h1n = h1T + ((t + 1) & 1) * 65536;
    float* h2p = h2T + (t & 1) * 65536;
    float* h2n = h2T + ((t + 1) & 1) * 65536;
    fb_gemm<0><<<256, 256, 0, stream>>>(ginT, Wv, bv, vT, 1024, 1024, nullptr, 0);
    fb_gemm<0><<<256, 256, 0, stream>>>(vT, Wo, bo, xaT, 1024, 1024, nullptr, 0);
    fb_gru<<<256, 256, 0, stream>>>(xaT, h1p, Wih0, Whh0, bih0, bhh0, h1n);
    fb_gru<<<256, 256, 0, stream>>>(h1n, h2p, Wih1, Whh1, bih1, bhh1, h2n);
    fb_gemm<0><<<64, 256, 0, stream>>>(h2n, Wh, bh, nzT, 1024, 256, out, t);
    fb_gemm<1><<<256, 256, 0, stream>>>(nzT, w1, b1, t1T, 256, 1024, nullptr, 0);
    fb_gemm<1><<<256, 256, 0, stream>>>(t1T, w2, b2, ginT, 1024, 1024, nullptr, 0);
  }
}